// Round 5
// baseline (509.641 us; speedup 1.0000x reference)
//
#include <hip/hip_runtime.h>
#include <hip/hip_bf16.h>
#include <math.h>

#define BB 2
#define QQ 300
#define TT 300
#define HH 256
#define WW 256
#define PP 12544
#define NCHUNK 16                     // 16-row y-buckets
#define NSPLIT 14
#define KSPLIT (PP / NSPLIT)          // 896
#define KSTEPS (KSPLIT / 64)          // 14 steps of BK=64

typedef __bf16 bf16_t;
typedef bf16_t bf16x8 __attribute__((ext_vector_type(8)));
typedef float floatx4 __attribute__((ext_vector_type(4)));

__device__ inline void gl_lds16(const void* g, void* l) {
    __builtin_amdgcn_global_load_lds(
        (const __attribute__((address_space(1))) unsigned int*)g,
        (__attribute__((address_space(3))) unsigned int*)l, 16, 0, 0);
}

// ---------------- kernel 1: bilinear offsets/weights + bucket + global histogram ----------------
__global__ __launch_bounds__(256) void prep_kernel(const float* __restrict__ pts,
                                                   int4* __restrict__ off,
                                                   float4* __restrict__ wgt,
                                                   int* __restrict__ bkt,
                                                   int* __restrict__ hist) {
    int idx = blockIdx.x * 256 + threadIdx.x;   // grid sized exactly BB*PP
    int b = idx / PP;
    float px = pts[idx * 2 + 0];
    float py = pts[idx * 2 + 1];
    float x = px * WW - 0.5f;
    float y = py * HH - 0.5f;
    float x0f = floorf(x), y0f = floorf(y);
    float wx = x - x0f, wy = y - y0f;
    int x0 = (int)x0f, y0 = (int)y0f;
    int x1 = x0 + 1, y1 = y0 + 1;
    float vx0 = (x0 >= 0 && x0 < WW) ? 1.f : 0.f;
    float vx1 = (x1 >= 0 && x1 < WW) ? 1.f : 0.f;
    float vy0 = (y0 >= 0 && y0 < HH) ? 1.f : 0.f;
    float vy1 = (y1 >= 0 && y1 < HH) ? 1.f : 0.f;
    int cx0 = min(max(x0, 0), WW - 1), cx1 = min(max(x1, 0), WW - 1);
    int cy0 = min(max(y0, 0), HH - 1), cy1 = min(max(y1, 0), HH - 1);
    off[idx] = make_int4(cy0 * WW + cx0, cy0 * WW + cx1, cy1 * WW + cx0, cy1 * WW + cx1);
    wgt[idx] = make_float4((1.f - wy) * (1.f - wx) * vy0 * vx0,
                           (1.f - wy) * wx        * vy0 * vx1,
                           wy        * (1.f - wx) * vy1 * vx0,
                           wy        * wx         * vy1 * vx1);
    int c = min(max(y0, 0), HH - 2) >> 4;   // rows y0,y0+1 within [16c, 16c+16]
    bkt[idx] = c;
    atomicAdd(&hist[b * NCHUNK + c], 1);
}

// ---------------- kernel 1b: tiny scan of the 16-bin histograms ----------------
__global__ void scan_kernel(const int* __restrict__ hist,
                            int* __restrict__ cs, int* __restrict__ gbase) {
    int b = threadIdx.x;
    if (b >= BB) return;
    int run = 0;
    for (int i = 0; i < NCHUNK; ++i) {
        cs[b * (NCHUNK + 1) + i] = run;
        gbase[b * NCHUNK + i] = run;
        run += hist[b * NCHUNK + i];
    }
    cs[b * (NCHUNK + 1) + NCHUNK] = run;   // == PP
}

// ---------------- kernel 1c: ballot-aggregated scatter into bucket order ----------------
__global__ __launch_bounds__(256) void scatter_kernel(const int4* __restrict__ off,
                                                      const float4* __restrict__ wgt,
                                                      const int* __restrict__ bkt,
                                                      int* __restrict__ gbase,
                                                      int4* __restrict__ off_s,
                                                      float4* __restrict__ wgt_s) {
    int idx = blockIdx.x * 256 + threadIdx.x;   // exactly BB*PP; PP % 256 == 0
    int b = idx / PP;                            // wave-uniform
    int lane = threadIdx.x & 63;
    int my = bkt[idx];
    int pos = 0;
    for (int c = 0; c < NCHUNK; ++c) {
        bool active = (my == c);
        unsigned long long mask = __ballot(active);
        if (mask == 0ull) continue;
        int leader = __ffsll((unsigned long long)mask) - 1;
        int base_v = 0;
        if (lane == leader) base_v = atomicAdd(&gbase[b * NCHUNK + c], (int)__popcll(mask));
        base_v = __shfl(base_v, leader, 64);
        if (active) pos = base_v + (int)__popcll(mask & (((unsigned long long)1 << lane) - 1ull));
    }
    off_s[(size_t)b * PP + pos] = off[idx];
    wgt_s[(size_t)b * PP + pos] = wgt[idx];
}

// ---------------- kernel 2: point-sample; one block per (mask-pair, chunk) ----------------
// Block handles pred_masks[m] AND tgt_masks[m] for one 16-row chunk: one staging
// phase fills both 17-row windows (34 KB LDS) via global_load_lds; point off/wgt are
// register-prefetched BEFORE the barrier so L2 latency hides under the HBM drain.
__global__ __launch_bounds__(256) void sample_kernel(
    const float* __restrict__ pred_masks, const float* __restrict__ tgt_masks,
    const int4* __restrict__ off_s, const float4* __restrict__ wgt_s,
    const int* __restrict__ cs_g,
    bf16_t* __restrict__ OM, bf16_t* __restrict__ SM, bf16_t* __restrict__ TM,
    float* __restrict__ RS_SP, float* __restrict__ RS_S, float* __restrict__ RS_T) {
    int b = blockIdx.z;
    int m = blockIdx.x;   // 0..299: pred m and tgt m
    int c = blockIdx.y;   // chunk
    int tid = threadIdx.x;
    int wave = tid >> 6, lane = tid & 63;
    __shared__ __align__(16) float rows[2 * 17 * WW];   // [pred | tgt], 34.8 KB

    const float* ip = pred_masks + (size_t)(b * QQ + m) * (HH * WW);
    const float* it = tgt_masks  + (size_t)(b * TT + m) * (HH * WW);
    bf16_t* rowO = OM + (size_t)(b * QQ + m) * PP;
    bf16_t* rowS = SM + (size_t)(b * QQ + m) * PP;
    bf16_t* rowT = TM + (size_t)(b * TT + m) * PP;

    int base = c * 16;
    int nrows = min(17, HH - base);        // 17, except 16 for the last chunk
    const char* gp = (const char*)(ip + base * WW);
    const char* gt = (const char*)(it + base * WW);
    // one row = 256 floats = 1024 B = one wave-issue (64 lanes x 16 B)
    for (int i = wave; i < nrows; i += 4) {
        gl_lds16(gp + i * 1024 + lane * 16, (char*)rows + i * 1024);
        gl_lds16(gt + i * 1024 + lane * 16, (char*)rows + 17408 + i * 1024);
    }

    // prefetch point data while the stage drains (no LDS dependence)
    const int4*  offb = off_s + (size_t)b * PP;
    const float4* wb  = wgt_s + (size_t)b * PP;
    const int* cs = cs_g + b * (NCHUNK + 1);
    int j0 = cs[c], j1 = cs[c + 1];
    int4 o_r[4]; float4 w_r[4];
    int np = 0;
    for (int j = j0 + tid; j < j1 && np < 4; j += 256) {
        o_r[np] = offb[j];
        w_r[np] = wb[j];
        ++np;
    }
    __syncthreads();

    int boff = base * WW;
    float s0 = 0.f, s1 = 0.f, s2 = 0.f;
    for (int i = 0; i < np; ++i) {
        int j = j0 + tid + i * 256;
        int4 o = o_r[i];
        float4 w = w_r[i];
        int ox = o.x - boff, oy = o.y - boff, oz = o.z - boff, ow = o.w - boff;
        float v = w.x * rows[ox] + w.y * rows[oy] + w.z * rows[oz] + w.w * rows[ow];
        float u = w.x * rows[4352 + ox] + w.y * rows[4352 + oy] +
                  w.z * rows[4352 + oz] + w.w * rows[4352 + ow];
        rowO[j] = (bf16_t)v;
        float e = __expf(-fabsf(v));
        float r = 1.f / (1.f + e);
        float sg = (v >= 0.f) ? r : e * r;
        rowS[j] = (bf16_t)sg;
        s0 += fmaxf(v, 0.f) + __logf(1.f + e);   // stable softplus
        s1 += sg;
        rowT[j] = (bf16_t)u;
        s2 += u;
    }
    // safety tail (buckets >1024 points never happen with these sizes)
    for (int j = j0 + tid + 4 * 256; j < j1; j += 256) {
        int4 o = offb[j];
        float4 w = wb[j];
        int ox = o.x - boff, oy = o.y - boff, oz = o.z - boff, ow = o.w - boff;
        float v = w.x * rows[ox] + w.y * rows[oy] + w.z * rows[oz] + w.w * rows[ow];
        float u = w.x * rows[4352 + ox] + w.y * rows[4352 + oy] +
                  w.z * rows[4352 + oz] + w.w * rows[4352 + ow];
        rowO[j] = (bf16_t)v;
        float e = __expf(-fabsf(v));
        float r = 1.f / (1.f + e);
        float sg = (v >= 0.f) ? r : e * r;
        rowS[j] = (bf16_t)sg;
        s0 += fmaxf(v, 0.f) + __logf(1.f + e);
        s1 += sg;
        rowT[j] = (bf16_t)u;
        s2 += u;
    }

    for (int o = 32; o > 0; o >>= 1) {
        s0 += __shfl_down(s0, o, 64);
        s1 += __shfl_down(s1, o, 64);
        s2 += __shfl_down(s2, o, 64);
    }
    __shared__ float ra[4], rb[4], rc[4];
    if (lane == 0) { ra[wave] = s0; rb[wave] = s1; rc[wave] = s2; }
    __syncthreads();
    if (tid == 0) {
        atomicAdd(&RS_SP[b * QQ + m], ra[0] + ra[1] + ra[2] + ra[3]);
        atomicAdd(&RS_S [b * QQ + m], rb[0] + rb[1] + rb[2] + rb[3]);
        atomicAdd(&RS_T [b * TT + m], rc[0] + rc[1] + rc[2] + rc[3]);
    }
}

// ---------------- kernel 3: LDS-staged dual bf16 MFMA GEMM, split-K ----------------
__global__ __launch_bounds__(256) void matmul_kernel(
    const bf16_t* __restrict__ OM, const bf16_t* __restrict__ SM, const bf16_t* __restrict__ TM,
    float* __restrict__ A1P, float* __restrict__ A2P) {
    int b = blockIdx.z / NSPLIT;
    int split = blockIdx.z % NSPLIT;
    int m0 = blockIdx.x * 64;
    int n0 = blockIdx.y * 64;
    int tid = threadIdx.x;
    int wave = tid >> 6, lane = tid & 63;
    int lrow = lane & 15, quad = lane >> 4;

    __shared__ __align__(16) bf16_t lds[3 * 64 * 64];   // [A1 | A2 | B]

    int k0 = split * KSPLIT;
    int lr8 = lane >> 3;           // row within 8-row group
    int clog = (lane & 7) ^ lr8;   // swizzled logical chunk this lane fetches

    const char* gp[6];
    unsigned lofs[6];
#pragma unroll
    for (int jj = 0; jj < 6; ++jj) {
        int L = wave + jj * 4;     // 24 wave-loads: 3 matrices x 8 row-groups
        int mat = L >> 3, i = L & 7;
        int rb_ = (mat == 2) ? n0 : m0;
        int row = min(rb_ + i * 8 + lr8, (mat == 2) ? (TT - 1) : (QQ - 1));
        const bf16_t* g = (mat == 0) ? OM + (size_t)b * QQ * PP
                        : (mat == 1) ? SM + (size_t)b * QQ * PP
                                     : TM + (size_t)b * TT * PP;
        gp[jj] = (const char*)(g + (size_t)row * PP + k0) + clog * 16;
        lofs[jj] = mat * 4096 + i * 512;   // 8 rows x 64 bf16 per group
    }

    floatx4 acc1[4] = {{0.f,0.f,0.f,0.f},{0.f,0.f,0.f,0.f},{0.f,0.f,0.f,0.f},{0.f,0.f,0.f,0.f}};
    floatx4 acc2[4] = {{0.f,0.f,0.f,0.f},{0.f,0.f,0.f,0.f},{0.f,0.f,0.f,0.f},{0.f,0.f,0.f,0.f}};

    int ar = wave * 16 + lrow;
    int arx = ar & 7;
    for (int s = 0; s < KSTEPS; ++s) {
#pragma unroll
        for (int jj = 0; jj < 6; ++jj) {
            gl_lds16(gp[jj], lds + lofs[jj]);
            gp[jj] += 128;   // 64 bf16
        }
        __syncthreads();
#pragma unroll
        for (int kk8 = 0; kk8 <= 4; kk8 += 4) {   // two K=32 halves of BK=64
            bf16x8 a1 = *(const bf16x8*)(lds + ar * 64 + (((quad + kk8) ^ arx) << 3));
            bf16x8 a2 = *(const bf16x8*)(lds + 4096 + ar * 64 + (((quad + kk8) ^ arx) << 3));
#pragma unroll
            for (int j = 0; j < 4; ++j) {
                int br = j * 16 + lrow;
                bf16x8 bb = *(const bf16x8*)(lds + 8192 + br * 64 + (((quad + kk8) ^ (br & 7)) << 3));
                acc1[j] = __builtin_amdgcn_mfma_f32_16x16x32_bf16(a1, bb, acc1[j], 0, 0, 0);
                acc2[j] = __builtin_amdgcn_mfma_f32_16x16x32_bf16(a2, bb, acc2[j], 0, 0, 0);
            }
        }
        __syncthreads();
    }

    // C/D layout: col = lane&15, row = quad*4 + reg
    int mrow = m0 + wave * 16 + quad * 4;
    float* o1 = A1P + (size_t)(b * NSPLIT + split) * (QQ * TT);
    float* o2 = A2P + (size_t)(b * NSPLIT + split) * (QQ * TT);
#pragma unroll
    for (int j = 0; j < 4; ++j) {
        int n = n0 + j * 16 + lrow;
        if (n < TT) {
#pragma unroll
            for (int r = 0; r < 4; ++r) {
                int m = mrow + r;
                if (m < QQ) {
                    o1[m * TT + n] = acc1[j][r];
                    o2[m * TT + n] = acc2[j][r];
                }
            }
        }
    }
}

// ---------------- kernel 4: reduce splits + mask/dice/bbox/giou combine ----------------
__global__ __launch_bounds__(256) void combine_kernel(
    const float* __restrict__ A1P, const float* __restrict__ A2P,
    const float* __restrict__ RS_SP, const float* __restrict__ RS_S, const float* __restrict__ RS_T,
    const float* __restrict__ pred_boxes, const float* __restrict__ tgt_boxes,
    float* __restrict__ out) {
    int idx = blockIdx.x * 256 + threadIdx.x;
    if (idx >= BB * QQ * TT) return;
    int b = idx / (QQ * TT);
    int r = idx - b * (QQ * TT);
    int q = r / TT;
    int t = r - q * TT;

    float a1 = 0.f, a2 = 0.f;
#pragma unroll
    for (int s = 0; s < NSPLIT; ++s) {
        a1 += A1P[(size_t)(b * NSPLIT + s) * (QQ * TT) + r];
        a2 += A2P[(size_t)(b * NSPLIT + s) * (QQ * TT) + r];
    }
    float cm = (RS_SP[b * QQ + q] - a1) * (1.0f / (float)PP);
    float cd = 1.f - (2.f * a2 + 1.f) / (RS_S[b * QQ + q] + RS_T[b * TT + t] + 1.f);

    const float* pb = pred_boxes + (size_t)(b * QQ + q) * 4;
    const float* tb = tgt_boxes + (size_t)(b * TT + t) * 4;
    float cb = fabsf(pb[0] - tb[0]) + fabsf(pb[1] - tb[1]) +
               fabsf(pb[2] - tb[2]) + fabsf(pb[3] - tb[3]);

    float ax0 = pb[0] - 0.5f * pb[2], ay0 = pb[1] - 0.5f * pb[3];
    float ax1 = pb[0] + 0.5f * pb[2], ay1 = pb[1] + 0.5f * pb[3];
    float bx0 = tb[0] - 0.5f * tb[2], by0 = tb[1] - 0.5f * tb[3];
    float bx1 = tb[0] + 0.5f * tb[2], by1 = tb[1] + 0.5f * tb[3];
    float area_a = (ax1 - ax0) * (ay1 - ay0);
    float area_b = (bx1 - bx0) * (by1 - by0);
    float iw = fmaxf(fminf(ax1, bx1) - fmaxf(ax0, bx0), 0.f);
    float ih = fmaxf(fminf(ay1, by1) - fmaxf(ay0, by0), 0.f);
    float inter = iw * ih;
    float uni = area_a + area_b - inter;
    float iou = inter / uni;
    float ew = fmaxf(ax1, bx1) - fminf(ax0, bx0);
    float eh = fmaxf(ay1, by1) - fminf(ay0, by0);
    float area_e = ew * eh;
    float giou = iou - (area_e - uni) / area_e;

    out[idx] = 5.f * cm + 5.f * cd + 5.f * cb - 2.f * giou;
}

extern "C" void kernel_launch(void* const* d_in, const int* in_sizes, int n_in,
                              void* d_out, int out_size, void* d_ws, size_t ws_size,
                              hipStream_t stream) {
    const float* pred_masks = (const float*)d_in[0];
    const float* tgt_masks  = (const float*)d_in[1];
    const float* pred_boxes = (const float*)d_in[2];
    const float* tgt_boxes  = (const float*)d_in[3];
    const float* pts        = (const float*)d_in[4];

    char* w = (char*)d_ws;
    auto alloc = [&](size_t bytes) -> char* {
        char* r = w;
        w += (bytes + 255) & ~(size_t)255;
        return r;
    };
    int4*   OFF   = (int4*)  alloc((size_t)BB * PP * sizeof(int4));
    float4* WGT   = (float4*)alloc((size_t)BB * PP * sizeof(float4));
    int*    BKT   = (int*)   alloc((size_t)BB * PP * sizeof(int));
    int4*   OFF_S = (int4*)  alloc((size_t)BB * PP * sizeof(int4));
    float4* WGT_S = (float4*)alloc((size_t)BB * PP * sizeof(float4));
    int*    CS    = (int*)   alloc((size_t)BB * (NCHUNK + 1) * sizeof(int));
    bf16_t* OM    = (bf16_t*)alloc((size_t)BB * QQ * PP * 2);
    bf16_t* SM    = (bf16_t*)alloc((size_t)BB * QQ * PP * 2);
    bf16_t* TM    = (bf16_t*)alloc((size_t)BB * TT * PP * 2);
    // zero-init region starts here (RS sums + histogram + scatter counters)
    float*  RS_SP = (float*) alloc((size_t)BB * QQ * 4);
    float*  RS_S  = (float*) alloc((size_t)BB * QQ * 4);
    float*  RS_T  = (float*) alloc((size_t)BB * TT * 4);
    int*    HIST  = (int*)   alloc((size_t)BB * NCHUNK * sizeof(int));
    int*    GBASE = (int*)   alloc((size_t)BB * NCHUNK * sizeof(int));
    float*  A1P   = (float*) alloc((size_t)BB * NSPLIT * QQ * TT * 4);
    float*  A2P   = (float*) alloc((size_t)BB * NSPLIT * QQ * TT * 4);

    hipMemsetAsync(RS_SP, 0, (size_t)((char*)A1P - (char*)RS_SP), stream);

    prep_kernel<<<(BB * PP) / 256, 256, 0, stream>>>(pts, OFF, WGT, BKT, HIST);
    scan_kernel<<<1, 64, 0, stream>>>(HIST, CS, GBASE);
    scatter_kernel<<<(BB * PP) / 256, 256, 0, stream>>>(OFF, WGT, BKT, GBASE, OFF_S, WGT_S);
    sample_kernel<<<dim3(QQ, NCHUNK, BB), 256, 0, stream>>>(
        pred_masks, tgt_masks, OFF_S, WGT_S, CS, OM, SM, TM, RS_SP, RS_S, RS_T);
    matmul_kernel<<<dim3(5, 5, BB * NSPLIT), 256, 0, stream>>>(OM, SM, TM, A1P, A2P);
    combine_kernel<<<(BB * QQ * TT + 255) / 256, 256, 0, stream>>>(
        A1P, A2P, RS_SP, RS_S, RS_T, pred_boxes, tgt_boxes, (float*)d_out);
}

// Round 6
// 413.213 us; speedup vs baseline: 1.2334x; 1.2334x over previous
//
#include <hip/hip_runtime.h>
#include <hip/hip_bf16.h>
#include <math.h>

#define BB 2
#define QQ 300
#define TT 300
#define HH 256
#define WW 256
#define PP 12544
#define NCHUNK 16                     // 16-row y-buckets
#define NSPLIT 14
#define KSPLIT (PP / NSPLIT)          // 896
#define KSTEPS (KSPLIT / 64)          // 14 steps of BK=64

typedef __bf16 bf16_t;
typedef bf16_t bf16x8 __attribute__((ext_vector_type(8)));
typedef float floatx4 __attribute__((ext_vector_type(4)));

__device__ inline void gl_lds16(const void* g, void* l) {
    __builtin_amdgcn_global_load_lds(
        (const __attribute__((address_space(1))) unsigned int*)g,
        (__attribute__((address_space(3))) unsigned int*)l, 16, 0, 0);
}

// ---------------- kernel 1: bilinear offsets/weights + bucket + histogram ----------------
__global__ __launch_bounds__(256) void prep_kernel(const float* __restrict__ pts,
                                                   int4* __restrict__ off,
                                                   float4* __restrict__ wgt,
                                                   int* __restrict__ bkt,
                                                   int* __restrict__ hist) {
    int idx = blockIdx.x * 256 + threadIdx.x;   // grid sized exactly BB*PP
    int b = idx / PP;
    __shared__ int lh[NCHUNK];
    if (threadIdx.x < NCHUNK) lh[threadIdx.x] = 0;
    __syncthreads();
    float px = pts[idx * 2 + 0];
    float py = pts[idx * 2 + 1];
    float x = px * WW - 0.5f;
    float y = py * HH - 0.5f;
    float x0f = floorf(x), y0f = floorf(y);
    float wx = x - x0f, wy = y - y0f;
    int x0 = (int)x0f, y0 = (int)y0f;
    int x1 = x0 + 1, y1 = y0 + 1;
    float vx0 = (x0 >= 0 && x0 < WW) ? 1.f : 0.f;
    float vx1 = (x1 >= 0 && x1 < WW) ? 1.f : 0.f;
    float vy0 = (y0 >= 0 && y0 < HH) ? 1.f : 0.f;
    float vy1 = (y1 >= 0 && y1 < HH) ? 1.f : 0.f;
    int cx0 = min(max(x0, 0), WW - 1), cx1 = min(max(x1, 0), WW - 1);
    int cy0 = min(max(y0, 0), HH - 1), cy1 = min(max(y1, 0), HH - 1);
    off[idx] = make_int4(cy0 * WW + cx0, cy0 * WW + cx1, cy1 * WW + cx0, cy1 * WW + cx1);
    wgt[idx] = make_float4((1.f - wy) * (1.f - wx) * vy0 * vx0,
                           (1.f - wy) * wx        * vy0 * vx1,
                           wy        * (1.f - wx) * vy1 * vx0,
                           wy        * wx         * vy1 * vx1);
    int c = min(max(y0, 0), HH - 2) >> 4;   // rows y0,y0+1 within [16c, 16c+16]
    bkt[idx] = c;
    atomicAdd(&lh[c], 1);                    // block is batch-uniform (PP % 256 == 0)
    __syncthreads();
    if (threadIdx.x < NCHUNK && lh[threadIdx.x] > 0)
        atomicAdd(&hist[b * NCHUNK + threadIdx.x], lh[threadIdx.x]);
}

// ---------------- kernel 1b: tiny scan of the 16-bin histograms ----------------
__global__ void scan_kernel(const int* __restrict__ hist,
                            int* __restrict__ cs, int* __restrict__ gbase) {
    int b = threadIdx.x;
    if (b >= BB) return;
    int run = 0;
    for (int i = 0; i < NCHUNK; ++i) {
        cs[b * (NCHUNK + 1) + i] = run;
        gbase[b * NCHUNK + i] = run;
        run += hist[b * NCHUNK + i];
    }
    cs[b * (NCHUNK + 1) + NCHUNK] = run;   // == PP
}

// ---------------- kernel 1c: ballot-aggregated scatter into bucket order ----------------
__global__ __launch_bounds__(256) void scatter_kernel(const int4* __restrict__ off,
                                                      const float4* __restrict__ wgt,
                                                      const int* __restrict__ bkt,
                                                      int* __restrict__ gbase,
                                                      int4* __restrict__ off_s,
                                                      float4* __restrict__ wgt_s) {
    int idx = blockIdx.x * 256 + threadIdx.x;   // exactly BB*PP; PP % 256 == 0
    int b = idx / PP;                            // wave-uniform
    int lane = threadIdx.x & 63;
    int my = bkt[idx];
    int pos = 0;
    for (int c = 0; c < NCHUNK; ++c) {
        bool active = (my == c);
        unsigned long long mask = __ballot(active);
        if (mask == 0ull) continue;
        int leader = __ffsll((unsigned long long)mask) - 1;
        int base_v = 0;
        if (lane == leader) base_v = atomicAdd(&gbase[b * NCHUNK + c], (int)__popcll(mask));
        base_v = __shfl(base_v, leader, 64);
        if (active) pos = base_v + (int)__popcll(mask & (((unsigned long long)1 << lane) - 1ull));
    }
    off_s[(size_t)b * PP + pos] = off[idx];
    wgt_s[(size_t)b * PP + pos] = wgt[idx];
}

// ---------------- kernel 2: point-sample; one block per (mask-pair, chunk) ----------------
// Block handles pred_masks[m] AND tgt_masks[m] for one 16-row chunk: one staging
// phase fills both 17-row windows (34 KB LDS) via global_load_lds; point off/wgt are
// register-prefetched (FULLY UNROLLED, compile-time indices -> stays in VGPRs, no
// scratch spill) before the barrier so L2 latency hides under the HBM drain.
__global__ __launch_bounds__(256) void sample_kernel(
    const float* __restrict__ pred_masks, const float* __restrict__ tgt_masks,
    const int4* __restrict__ off_s, const float4* __restrict__ wgt_s,
    const int* __restrict__ cs_g,
    bf16_t* __restrict__ OM, bf16_t* __restrict__ SM, bf16_t* __restrict__ TM,
    float* __restrict__ RS_SP, float* __restrict__ RS_S, float* __restrict__ RS_T) {
    int b = blockIdx.z;
    int m = blockIdx.x;   // 0..299: pred m and tgt m
    int c = blockIdx.y;   // chunk
    int tid = threadIdx.x;
    int wave = tid >> 6, lane = tid & 63;
    __shared__ __align__(16) float rows[2 * 17 * WW];   // [pred | tgt], 34.8 KB

    const float* ip = pred_masks + (size_t)(b * QQ + m) * (HH * WW);
    const float* it = tgt_masks  + (size_t)(b * TT + m) * (HH * WW);
    bf16_t* rowO = OM + (size_t)(b * QQ + m) * PP;
    bf16_t* rowS = SM + (size_t)(b * QQ + m) * PP;
    bf16_t* rowT = TM + (size_t)(b * TT + m) * PP;

    int base = c * 16;
    int nrows = min(17, HH - base);        // 17, except 16 for the last chunk
    const char* gp = (const char*)(ip + base * WW);
    const char* gt = (const char*)(it + base * WW);
    // one row = 256 floats = 1024 B = one wave-issue (64 lanes x 16 B)
    for (int i = wave; i < nrows; i += 4) {
        gl_lds16(gp + i * 1024 + lane * 16, (char*)rows + i * 1024);
        gl_lds16(gt + i * 1024 + lane * 16, (char*)rows + 17408 + i * 1024);
    }

    // prefetch point data while the stage drains (no LDS dependence)
    const int4*  offb = off_s + (size_t)b * PP;
    const float4* wb  = wgt_s + (size_t)b * PP;
    const int* cs = cs_g + b * (NCHUNK + 1);
    int j0 = cs[c], j1 = cs[c + 1];
    int4 o_r[4]; float4 w_r[4];
#pragma unroll
    for (int i = 0; i < 4; ++i) {
        int j = j0 + tid + i * 256;
        if (j < j1) { o_r[i] = offb[j]; w_r[i] = wb[j]; }
    }
    __syncthreads();

    int boff = base * WW;
    float s0 = 0.f, s1 = 0.f, s2 = 0.f;
#pragma unroll
    for (int i = 0; i < 4; ++i) {
        int j = j0 + tid + i * 256;
        if (j < j1) {
            int4 o = o_r[i];
            float4 w = w_r[i];
            int ox = o.x - boff, oy = o.y - boff, oz = o.z - boff, ow = o.w - boff;
            float v = w.x * rows[ox] + w.y * rows[oy] + w.z * rows[oz] + w.w * rows[ow];
            float u = w.x * rows[4352 + ox] + w.y * rows[4352 + oy] +
                      w.z * rows[4352 + oz] + w.w * rows[4352 + ow];
            rowO[j] = (bf16_t)v;
            float e = __expf(-fabsf(v));
            float r = 1.f / (1.f + e);
            float sg = (v >= 0.f) ? r : e * r;
            rowS[j] = (bf16_t)sg;
            s0 += fmaxf(v, 0.f) + __logf(1.f + e);   // stable softplus
            s1 += sg;
            rowT[j] = (bf16_t)u;
            s2 += u;
        }
    }
    // safety tail (buckets > 1024 points statistically never happen: max ~900)
    for (int j = j0 + tid + 4 * 256; j < j1; j += 256) {
        int4 o = offb[j];
        float4 w = wb[j];
        int ox = o.x - boff, oy = o.y - boff, oz = o.z - boff, ow = o.w - boff;
        float v = w.x * rows[ox] + w.y * rows[oy] + w.z * rows[oz] + w.w * rows[ow];
        float u = w.x * rows[4352 + ox] + w.y * rows[4352 + oy] +
                  w.z * rows[4352 + oz] + w.w * rows[4352 + ow];
        rowO[j] = (bf16_t)v;
        float e = __expf(-fabsf(v));
        float r = 1.f / (1.f + e);
        float sg = (v >= 0.f) ? r : e * r;
        rowS[j] = (bf16_t)sg;
        s0 += fmaxf(v, 0.f) + __logf(1.f + e);
        s1 += sg;
        rowT[j] = (bf16_t)u;
        s2 += u;
    }

    for (int o = 32; o > 0; o >>= 1) {
        s0 += __shfl_down(s0, o, 64);
        s1 += __shfl_down(s1, o, 64);
        s2 += __shfl_down(s2, o, 64);
    }
    __shared__ float ra[4], rb[4], rc[4];
    if (lane == 0) { ra[wave] = s0; rb[wave] = s1; rc[wave] = s2; }
    __syncthreads();
    if (tid == 0) {
        atomicAdd(&RS_SP[b * QQ + m], ra[0] + ra[1] + ra[2] + ra[3]);
        atomicAdd(&RS_S [b * QQ + m], rb[0] + rb[1] + rb[2] + rb[3]);
        atomicAdd(&RS_T [b * TT + m], rc[0] + rc[1] + rc[2] + rc[3]);
    }
}

// ---------------- kernel 3: LDS-staged dual bf16 MFMA GEMM, split-K ----------------
__global__ __launch_bounds__(256) void matmul_kernel(
    const bf16_t* __restrict__ OM, const bf16_t* __restrict__ SM, const bf16_t* __restrict__ TM,
    float* __restrict__ A1P, float* __restrict__ A2P) {
    int b = blockIdx.z / NSPLIT;
    int split = blockIdx.z % NSPLIT;
    int m0 = blockIdx.x * 64;
    int n0 = blockIdx.y * 64;
    int tid = threadIdx.x;
    int wave = tid >> 6, lane = tid & 63;
    int lrow = lane & 15, quad = lane >> 4;

    __shared__ __align__(16) bf16_t lds[3 * 64 * 64];   // [A1 | A2 | B]

    int k0 = split * KSPLIT;
    int lr8 = lane >> 3;           // row within 8-row group
    int clog = (lane & 7) ^ lr8;   // swizzled logical chunk this lane fetches

    const char* gp[6];
    unsigned lofs[6];
#pragma unroll
    for (int jj = 0; jj < 6; ++jj) {
        int L = wave + jj * 4;     // 24 wave-loads: 3 matrices x 8 row-groups
        int mat = L >> 3, i = L & 7;
        int rb_ = (mat == 2) ? n0 : m0;
        int row = min(rb_ + i * 8 + lr8, (mat == 2) ? (TT - 1) : (QQ - 1));
        const bf16_t* g = (mat == 0) ? OM + (size_t)b * QQ * PP
                        : (mat == 1) ? SM + (size_t)b * QQ * PP
                                     : TM + (size_t)b * TT * PP;
        gp[jj] = (const char*)(g + (size_t)row * PP + k0) + clog * 16;
        lofs[jj] = mat * 4096 + i * 512;   // 8 rows x 64 bf16 per group
    }

    floatx4 acc1[4] = {{0.f,0.f,0.f,0.f},{0.f,0.f,0.f,0.f},{0.f,0.f,0.f,0.f},{0.f,0.f,0.f,0.f}};
    floatx4 acc2[4] = {{0.f,0.f,0.f,0.f},{0.f,0.f,0.f,0.f},{0.f,0.f,0.f,0.f},{0.f,0.f,0.f,0.f}};

    int ar = wave * 16 + lrow;
    int arx = ar & 7;
    for (int s = 0; s < KSTEPS; ++s) {
#pragma unroll
        for (int jj = 0; jj < 6; ++jj) {
            gl_lds16(gp[jj], lds + lofs[jj]);
            gp[jj] += 128;   // 64 bf16
        }
        __syncthreads();
#pragma unroll
        for (int kk8 = 0; kk8 <= 4; kk8 += 4) {   // two K=32 halves of BK=64
            bf16x8 a1 = *(const bf16x8*)(lds + ar * 64 + (((quad + kk8) ^ arx) << 3));
            bf16x8 a2 = *(const bf16x8*)(lds + 4096 + ar * 64 + (((quad + kk8) ^ arx) << 3));
#pragma unroll
            for (int j = 0; j < 4; ++j) {
                int br = j * 16 + lrow;
                bf16x8 bb = *(const bf16x8*)(lds + 8192 + br * 64 + (((quad + kk8) ^ (br & 7)) << 3));
                acc1[j] = __builtin_amdgcn_mfma_f32_16x16x32_bf16(a1, bb, acc1[j], 0, 0, 0);
                acc2[j] = __builtin_amdgcn_mfma_f32_16x16x32_bf16(a2, bb, acc2[j], 0, 0, 0);
            }
        }
        __syncthreads();
    }

    // C/D layout: col = lane&15, row = quad*4 + reg
    int mrow = m0 + wave * 16 + quad * 4;
    float* o1 = A1P + (size_t)(b * NSPLIT + split) * (QQ * TT);
    float* o2 = A2P + (size_t)(b * NSPLIT + split) * (QQ * TT);
#pragma unroll
    for (int j = 0; j < 4; ++j) {
        int n = n0 + j * 16 + lrow;
        if (n < TT) {
#pragma unroll
            for (int r = 0; r < 4; ++r) {
                int m = mrow + r;
                if (m < QQ) {
                    o1[m * TT + n] = acc1[j][r];
                    o2[m * TT + n] = acc2[j][r];
                }
            }
        }
    }
}

// ---------------- kernel 4: reduce splits + mask/dice/bbox/giou combine ----------------
__global__ __launch_bounds__(256) void combine_kernel(
    const float* __restrict__ A1P, const float* __restrict__ A2P,
    const float* __restrict__ RS_SP, const float* __restrict__ RS_S, const float* __restrict__ RS_T,
    const float* __restrict__ pred_boxes, const float* __restrict__ tgt_boxes,
    float* __restrict__ out) {
    int idx = blockIdx.x * 256 + threadIdx.x;
    if (idx >= BB * QQ * TT) return;
    int b = idx / (QQ * TT);
    int r = idx - b * (QQ * TT);
    int q = r / TT;
    int t = r - q * TT;

    float a1 = 0.f, a2 = 0.f;
#pragma unroll
    for (int s = 0; s < NSPLIT; ++s) {
        a1 += A1P[(size_t)(b * NSPLIT + s) * (QQ * TT) + r];
        a2 += A2P[(size_t)(b * NSPLIT + s) * (QQ * TT) + r];
    }
    float cm = (RS_SP[b * QQ + q] - a1) * (1.0f / (float)PP);
    float cd = 1.f - (2.f * a2 + 1.f) / (RS_S[b * QQ + q] + RS_T[b * TT + t] + 1.f);

    const float* pb = pred_boxes + (size_t)(b * QQ + q) * 4;
    const float* tb = tgt_boxes + (size_t)(b * TT + t) * 4;
    float cb = fabsf(pb[0] - tb[0]) + fabsf(pb[1] - tb[1]) +
               fabsf(pb[2] - tb[2]) + fabsf(pb[3] - tb[3]);

    float ax0 = pb[0] - 0.5f * pb[2], ay0 = pb[1] - 0.5f * pb[3];
    float ax1 = pb[0] + 0.5f * pb[2], ay1 = pb[1] + 0.5f * pb[3];
    float bx0 = tb[0] - 0.5f * tb[2], by0 = tb[1] - 0.5f * tb[3];
    float bx1 = tb[0] + 0.5f * tb[2], by1 = tb[1] + 0.5f * tb[3];
    float area_a = (ax1 - ax0) * (ay1 - ay0);
    float area_b = (bx1 - bx0) * (by1 - by0);
    float iw = fmaxf(fminf(ax1, bx1) - fmaxf(ax0, bx0), 0.f);
    float ih = fmaxf(fminf(ay1, by1) - fmaxf(ay0, by0), 0.f);
    float inter = iw * ih;
    float uni = area_a + area_b - inter;
    float iou = inter / uni;
    float ew = fmaxf(ax1, bx1) - fminf(ax0, bx0);
    float eh = fmaxf(ay1, by1) - fminf(ay0, by0);
    float area_e = ew * eh;
    float giou = iou - (area_e - uni) / area_e;

    out[idx] = 5.f * cm + 5.f * cd + 5.f * cb - 2.f * giou;
}

extern "C" void kernel_launch(void* const* d_in, const int* in_sizes, int n_in,
                              void* d_out, int out_size, void* d_ws, size_t ws_size,
                              hipStream_t stream) {
    const float* pred_masks = (const float*)d_in[0];
    const float* tgt_masks  = (const float*)d_in[1];
    const float* pred_boxes = (const float*)d_in[2];
    const float* tgt_boxes  = (const float*)d_in[3];
    const float* pts        = (const float*)d_in[4];

    char* w = (char*)d_ws;
    auto alloc = [&](size_t bytes) -> char* {
        char* r = w;
        w += (bytes + 255) & ~(size_t)255;
        return r;
    };
    int4*   OFF   = (int4*)  alloc((size_t)BB * PP * sizeof(int4));
    float4* WGT   = (float4*)alloc((size_t)BB * PP * sizeof(float4));
    int*    BKT   = (int*)   alloc((size_t)BB * PP * sizeof(int));
    int4*   OFF_S = (int4*)  alloc((size_t)BB * PP * sizeof(int4));
    float4* WGT_S = (float4*)alloc((size_t)BB * PP * sizeof(float4));
    int*    CS    = (int*)   alloc((size_t)BB * (NCHUNK + 1) * sizeof(int));
    bf16_t* OM    = (bf16_t*)alloc((size_t)BB * QQ * PP * 2);
    bf16_t* SM    = (bf16_t*)alloc((size_t)BB * QQ * PP * 2);
    bf16_t* TM    = (bf16_t*)alloc((size_t)BB * TT * PP * 2);
    // zero-init region starts here (RS sums + histogram + scatter counters)
    float*  RS_SP = (float*) alloc((size_t)BB * QQ * 4);
    float*  RS_S  = (float*) alloc((size_t)BB * QQ * 4);
    float*  RS_T  = (float*) alloc((size_t)BB * TT * 4);
    int*    HIST  = (int*)   alloc((size_t)BB * NCHUNK * sizeof(int));
    int*    GBASE = (int*)   alloc((size_t)BB * NCHUNK * sizeof(int));
    float*  A1P   = (float*) alloc((size_t)BB * NSPLIT * QQ * TT * 4);
    float*  A2P   = (float*) alloc((size_t)BB * NSPLIT * QQ * TT * 4);

    hipMemsetAsync(RS_SP, 0, (size_t)((char*)A1P - (char*)RS_SP), stream);

    prep_kernel<<<(BB * PP) / 256, 256, 0, stream>>>(pts, OFF, WGT, BKT, HIST);
    scan_kernel<<<1, 64, 0, stream>>>(HIST, CS, GBASE);
    scatter_kernel<<<(BB * PP) / 256, 256, 0, stream>>>(OFF, WGT, BKT, GBASE, OFF_S, WGT_S);
    sample_kernel<<<dim3(QQ, NCHUNK, BB), 256, 0, stream>>>(
        pred_masks, tgt_masks, OFF_S, WGT_S, CS, OM, SM, TM, RS_SP, RS_S, RS_T);
    matmul_kernel<<<dim3(5, 5, BB * NSPLIT), 256, 0, stream>>>(OM, SM, TM, A1P, A2P);
    combine_kernel<<<(BB * QQ * TT + 255) / 256, 256, 0, stream>>>(
        A1P, A2P, RS_SP, RS_S, RS_T, pred_boxes, tgt_boxes, (float*)d_out);
}